// Round 14
// baseline (145.114 us; speedup 1.0000x reference)
//
#include <hip/hip_runtime.h>
#include <hip/hip_bf16.h>

// Deformable conv via FUSED implicit GEMM on MFMA.
// B=8, C=256, H=W=64, O=256, K=3.
// R14: dcn_fused restructured so each wave owns 16 M-rows x all 256 N.
//   Lane l lerps EXACTLY its MFMA A-fragment (row w*16+(l&15), ch l4*8 of the
//   32-ch K-slice) -> A never goes through LDS (no ds_write/ds_read/swizzle/
//   barrier for A). Only B is LDS-staged (GLL, double-buffered, counted
//   vmcnt(4) barrier keeping the 4 next-step gathers in flight).

#define HW 64
#define CCH 256
#define OCH 256
#define BB 8
#define KDIM 2304  // 9 * 256, order kk*256 + c

typedef __attribute__((ext_vector_type(8))) short bf16x8;
typedef __attribute__((ext_vector_type(8))) unsigned short u16x8;
typedef __attribute__((ext_vector_type(4))) float f32x4;
typedef __attribute__((ext_vector_type(2))) float f32x2;
typedef __attribute__((ext_vector_type(4))) unsigned short u16x4;
typedef __attribute__((ext_vector_type(4))) unsigned int u32x4;

static __device__ inline unsigned short f2bf(float f) {
  unsigned u = __builtin_bit_cast(unsigned, f);
  u += 0x7FFFu + ((u >> 16) & 1u);  // RNE
  return (unsigned short)(u >> 16);
}
static __device__ inline float bf2f(unsigned short s) {
  return __builtin_bit_cast(float, (unsigned)s << 16);
}
static __device__ inline unsigned cvt_pk_bf16(float lo, float hi) {
  unsigned r;
  asm("v_cvt_pk_bf16_f32 %0, %1, %2" : "=v"(r) : "v"(lo), "v"(hi));
  return r;
}

#define GLL16(gsrc, ldst)                                                      \
  __builtin_amdgcn_global_load_lds(                                           \
      (const __attribute__((address_space(1))) void*)(gsrc),                  \
      (__attribute__((address_space(3))) void*)(ldst), 16, 0, 0)

static __device__ inline int xcd_swz256(int bid) {
  return (bid & 7) * 32 + (bid >> 3);
}

// ---------------- prep_xpose: merged (validated R13) ----------------
__global__ __launch_bounds__(256) void prep_xpose(
    const float* __restrict__ x, const float* __restrict__ w_dcn,
    const float* __restrict__ w_off, unsigned short* __restrict__ xTbf,
    unsigned short* __restrict__ W2, unsigned short* __restrict__ Wop,
    unsigned short* __restrict__ zp) {
  const int tid = threadIdx.x;
  const int bid = blockIdx.x;
  if (bid < 2048) {
    __shared__ float t[64][65];
    const int ct = bid & 3;
    const int pt = (bid >> 2) & 63;
    const int b = bid >> 8;
#pragma unroll
    for (int i = 0; i < 16; ++i) {
      int cl = i * 4 + (tid >> 6);
      int p = tid & 63;
      t[cl][p] = x[(((b << 8) + ct * 64 + cl) << 12) + pt * 64 + p];
    }
    __syncthreads();
#pragma unroll
    for (int i = 0; i < 4; ++i) {
      int pl = i * 16 + (tid >> 4);
      int c4 = (tid & 15) * 4;
      u16x4 v;
      v[0] = f2bf(t[c4][pl]);
      v[1] = f2bf(t[c4 + 1][pl]);
      v[2] = f2bf(t[c4 + 2][pl]);
      v[3] = f2bf(t[c4 + 3][pl]);
      *(u16x4*)(xTbf + (((size_t)((b << 12) + pt * 64 + pl)) << 8) + ct * 64 +
                c4) = v;
    }
  } else {
    int i = (bid - 2048) * 256 + tid;
    if (i < 9 * 256 * 256) {
      int o = i / KDIM;
      int r = i - o * KDIM;
      int kk = r >> 8, c = r & 255;
      W2[i] = f2bf(w_dcn[((o << 8) + c) * 9 + kk]);
    }
    if (i < 32 * KDIM) {
      int n = i / KDIM;
      int r = i - n * KDIM;
      int kk = r >> 8, c = r & 255;
      Wop[i] = (n < 18) ? f2bf(w_off[((n << 8) + c) * 9 + kk]) : (unsigned short)0;
    }
    if (i < 512) zp[i] = 0;
  }
}

// ---------------- offset_gemm (validated R13) ----------------
__global__ __launch_bounds__(512) void offset_gemm(
    const unsigned short* __restrict__ xTbf, const unsigned short* __restrict__ Wop,
    const unsigned short* __restrict__ zp, const float* __restrict__ b_off,
    float* __restrict__ off_buf) {
  __shared__ short ldsA[2][128 * 32];
  __shared__ short ldsB[2][32 * 32];
  const int tid = threadIdx.x;
  const int lane = tid & 63;
  const int wid = __builtin_amdgcn_readfirstlane(tid >> 6);
  const int m0 = xcd_swz256(blockIdx.x) * 128;
  const int b = m0 >> 12;
  const unsigned short* xb = xTbf + ((size_t)b << 20);

  const int rS = tid >> 2;
  const int cS = tid & 3;
  const int posS = (m0 & 4095) + rS;
  const int hS = posS >> 6, wS = posS & 63;
  const int scS = (cS ^ ((rS >> 1) & 3)) * 8;
  const int rB = tid >> 2;
  const unsigned short* srcB =
      Wop + (size_t)rB * KDIM + ((tid & 3) ^ ((rB >> 1) & 3)) * 8;

  const int l15 = lane & 15, l4 = lane >> 4;
  const int rA = wid * 16 + l15;
  const int offA = rA * 32 + ((l4 ^ ((rA >> 1) & 3)) << 3);
  int offB[2];
#pragma unroll
  for (int f = 0; f < 2; ++f) {
    const int rb = f * 16 + l15;
    offB[f] = rb * 32 + ((l4 ^ ((rb >> 1) & 3)) << 3);
  }

  const f32x4 z = {0.f, 0.f, 0.f, 0.f};
  f32x4 acc[2];
  acc[0] = z;
  acc[1] = z;

  auto stage = [&](int buf, int t) {
    const int kk = t >> 3;
    const int c0 = (t & 7) * 32;
    const int dy = kk / 3 - 1, dx = kk - (kk / 3) * 3 - 1;
    const int y = hS + dy, xx = wS + dx;
    const bool valid = ((unsigned)y < 64u) && ((unsigned)xx < 64u);
    const unsigned short* src =
        valid ? xb + ((((y << 6) + xx) << 8) + c0 + scS) : zp + scS;
    GLL16(src, &ldsA[buf][tid * 8]);
    if (tid < 128) GLL16(srcB + t * 32, &ldsB[buf][tid * 8]);
  };

  stage(0, 0);
  __syncthreads();

  for (int t = 0; t < 72; ++t) {
    const int buf = t & 1;
    if (t < 71) stage(buf ^ 1, t + 1);
    bf16x8 af, bfr[2];
    af = *(const bf16x8*)&ldsA[buf][offA];
#pragma unroll
    for (int f = 0; f < 2; ++f) bfr[f] = *(const bf16x8*)&ldsB[buf][offB[f]];
#pragma unroll
    for (int j = 0; j < 2; ++j)
      acc[j] = __builtin_amdgcn_mfma_f32_16x16x32_bf16(af, bfr[j], acc[j],
                                                       0, 0, 0);
    __syncthreads();
  }

#pragma unroll
  for (int j = 0; j < 2; ++j) {
    const int col = j * 16 + l15;
    if (col < 18) {
      const float bias = b_off[col];
#pragma unroll
      for (int rr = 0; rr < 4; ++rr) {
        const int m = m0 + wid * 16 + l4 * 4 + rr;
        off_buf[(size_t)m * 18 + col] = acc[j][rr] + bias;
      }
    }
  }
}

// ---------------- dcn_fused (R14: register-direct A) ----------------
// BM=128, BN=256, BK=32, 72 K-steps. 512 threads = 8 waves; wave w owns
// rows [w*16, w*16+16), acc[16] (16x256 tile). Lane lerps its own A-fragment.
__global__ __launch_bounds__(512, 2) void dcn_fused(
    const unsigned short* __restrict__ xTbf, const float* __restrict__ off_buf,
    const unsigned short* __restrict__ W2, float* __restrict__ out) {
  __shared__ f32x2 slyx[128][9];       // (ly, lx)             9.2KB
  __shared__ u16x4 spos[128][9];       // pos12 | valid<<15    9.2KB
  __shared__ short ldsB[2][256 * 32];  // B double buffer      32KB

  const int tid = threadIdx.x;
  const int lane = tid & 63;
  const int wid = __builtin_amdgcn_readfirstlane(tid >> 6);
  const int m0 = xcd_swz256(blockIdx.x) * 128;
  const int b = m0 >> 12;
  const unsigned short* xb = xTbf + ((size_t)b << 20);

  // ---- phase 0: sampling params for 128 rows x 9 taps ----
  for (int idx = tid; idx < 128 * 9; idx += 512) {
    const int r = idx / 9, k = idx - (idx / 9) * 9;
    const int ky = k / 3, kx = k - ky * 3;
    const int pos = (m0 & 4095) + r;
    const int h = pos >> 6, w = pos & 63;
    const float offy = off_buf[(size_t)(m0 + r) * 18 + 2 * k];
    const float offx = off_buf[(size_t)(m0 + r) * 18 + 2 * k + 1];
    const float sy = offy + (float)(h - 1 + ky);
    const float sx = offx + (float)(w - 1 + kx);
    const float y0f = floorf(sy), x0f = floorf(sx);
    const int y0 = (int)y0f, x0 = (int)x0f;
    const int y1 = y0 + 1, x1 = x0 + 1;
    const unsigned vy0 = ((unsigned)y0 < 64u), vy1 = ((unsigned)y1 < 64u);
    const unsigned vx0 = ((unsigned)x0 < 64u), vx1 = ((unsigned)x1 < 64u);
    const int y0c = min(max(y0, 0), HW - 1), y1c = min(max(y1, 0), HW - 1);
    const int x0c = min(max(x0, 0), HW - 1), x1c = min(max(x1, 0), HW - 1);
    f32x2 lyx;
    lyx[0] = sy - y0f;
    lyx[1] = sx - x0f;
    u16x4 pp;
    pp[0] = (unsigned short)(((y0c << 6) + x0c) | ((vy0 & vx0) << 15));
    pp[1] = (unsigned short)(((y0c << 6) + x1c) | ((vy0 & vx1) << 15));
    pp[2] = (unsigned short)(((y1c << 6) + x0c) | ((vy1 & vx0) << 15));
    pp[3] = (unsigned short)(((y1c << 6) + x1c) | ((vy1 & vx1) << 15));
    slyx[r][k] = lyx;
    spos[r][k] = pp;
  }

  // ---- roles ----
  const int l15 = lane & 15, l4 = lane >> 4;
  const int l48 = l4 * 8;                 // lane's 8-ch slot in the 32-k slice
  const int rlane = wid * 16 + l15;       // lane's M-row (param index)

  // B staging: 2 GLL16/thread; dst lane-linear, source chunk pre-swizzled.
  const unsigned short* srcBp[2];
#pragma unroll
  for (int g = 0; g < 2; ++g) {
    const int idx = g * 512 + tid;
    const int row = idx >> 2, c = idx & 3;
    srcBp[g] = W2 + (size_t)row * KDIM + ((c ^ ((row >> 1) & 3)) << 3);
  }
  const int dstB0 = tid * 8, dstB1 = (512 + tid) * 8;

  int offB[16];
#pragma unroll
  for (int j = 0; j < 16; ++j) {
    const int rB = j * 16 + l15;
    offB[j] = rB * 32 + ((l4 ^ ((rB >> 1) & 3)) << 3);
  }

  const f32x4 z = {0.f, 0.f, 0.f, 0.f};
  f32x4 acc[16];
#pragma unroll
  for (int j = 0; j < 16; ++j) acc[j] = z;

  __syncthreads();  // params visible

  // per-tap params for the lane's row
  f32x4 wv;
  int av[4];
  auto load_params = [&](int tap) {
    const f32x2 lyx = slyx[rlane][tap];
    const u16x4 pp = spos[rlane][tap];
    const float ly = lyx[0], lx = lyx[1];
#pragma unroll
    for (int e = 0; e < 4; ++e) av[e] = (int)(pp[e] & 0x0FFFu) << 8;
    wv[0] = (1.f - ly) * (1.f - lx) * (float)(pp[0] >> 15);
    wv[1] = (1.f - ly) * lx * (float)(pp[1] >> 15);
    wv[2] = ly * (1.f - lx) * (float)(pp[2] >> 15);
    wv[3] = ly * lx * (float)(pp[3] >> 15);
  };

  auto lerp_frag = [&](const u16x8& c0, const u16x8& c1, const u16x8& c2,
                       const u16x8& c3, const f32x4& w) -> bf16x8 {
    u32x4 words;
#pragma unroll
    for (int e = 0; e < 4; ++e) {
      const float f0 = w[0] * bf2f(c0[2 * e]) + w[1] * bf2f(c1[2 * e]) +
                       w[2] * bf2f(c2[2 * e]) + w[3] * bf2f(c3[2 * e]);
      const float f1 = w[0] * bf2f(c0[2 * e + 1]) + w[1] * bf2f(c1[2 * e + 1]) +
                       w[2] * bf2f(c2[2 * e + 1]) + w[3] * bf2f(c3[2 * e + 1]);
      words[e] = cvt_pk_bf16(f0, f1);
    }
    return __builtin_bit_cast(bf16x8, words);
  };

  // 2 gather register sets (ping-pong); weight carried with each set.
  u16x8 gA[4], gB[4];
  f32x4 wA, wB;

  // ---- prologue: params(0), gathers(0)->gA, B(0) staged, full drain ----
  load_params(0);
  gA[0] = *(const u16x8*)(xb + av[0] + l48);
  gA[1] = *(const u16x8*)(xb + av[1] + l48);
  gA[2] = *(const u16x8*)(xb + av[2] + l48);
  gA[3] = *(const u16x8*)(xb + av[3] + l48);
  wA = wv;
  GLL16(srcBp[0], &ldsB[0][dstB0]);
  GLL16(srcBp[1], &ldsB[0][dstB1]);
  asm volatile("s_waitcnt vmcnt(0) lgkmcnt(0)" ::: "memory");
  __builtin_amdgcn_s_barrier();
  __builtin_amdgcn_sched_barrier(0);

// step T (0..70): stage B(T+1); gather(T+1)->COUT; lerp(T) from CIN; 16 MFMA
// on B(T); barrier vmcnt(4) (drains 2 GLL, keeps 4 gathers in flight).
#define FSTEP(T, CIN, WIN, COUT, WOUT)                                         \
  {                                                                            \
    GLL16(srcBp[0] + ((T) + 1) * 32, &ldsB[((T) + 1) & 1][dstB0]);             \
    GLL16(srcBp[1] + ((T) + 1) * 32, &ldsB[((T) + 1) & 1][dstB1]);             \
    __builtin_amdgcn_sched_barrier(0);                                         \
    if ((((T) + 1) & 7) == 0) load_params(((T) + 1) >> 3);                     \
    {                                                                          \
      const int chb = ((((T) + 1) & 7) << 5) + l48;                            \
      COUT[0] = *(const u16x8*)(xb + av[0] + chb);                             \
      COUT[1] = *(const u16x8*)(xb + av[1] + chb);                             \
      COUT[2] = *(const u16x8*)(xb + av[2] + chb);                             \
      COUT[3] = *(const u16x8*)(xb + av[3] + chb);                             \
      WOUT = wv;                                                               \
    }                                                                          \
    const bf16x8 afrag = lerp_frag(CIN[0], CIN[1], CIN[2], CIN[3], WIN);       \
    bf16x8 bfr[16];                                                            \
    _Pragma("unroll") for (int j = 0; j < 16; ++j)                             \
        bfr[j] = *(const bf16x8*)&ldsB[(T) & 1][offB[j]];                      \
    __builtin_amdgcn_s_setprio(1);                                             \
    _Pragma("unroll") for (int j = 0; j < 16; ++j)                             \
        acc[j] = __builtin_amdgcn_mfma_f32_16x16x32_bf16(afrag, bfr[j],        \
                                                         acc[j], 0, 0, 0);     \
    __builtin_amdgcn_s_setprio(0);                                             \
    asm volatile("s_waitcnt vmcnt(4) lgkmcnt(0)" ::: "memory");                \
    __builtin_amdgcn_s_barrier();                                              \
    __builtin_amdgcn_sched_barrier(0);                                         \
  }

  int t = 0;
  for (int it = 0; it < 35; ++it) {
    FSTEP(t, gA, wA, gB, wB) ++t;
    FSTEP(t, gB, wB, gA, wA) ++t;
  }
  FSTEP(70, gA, wA, gB, wB)  // prefetches tile 71 into gB
#undef FSTEP

  // ---- t = 71: consume gB + ldsB[1], no prefetch/barrier ----
  {
    const bf16x8 afrag = lerp_frag(gB[0], gB[1], gB[2], gB[3], wB);
    bf16x8 bfr[16];
#pragma unroll
    for (int j = 0; j < 16; ++j) bfr[j] = *(const bf16x8*)&ldsB[1][offB[j]];
#pragma unroll
    for (int j = 0; j < 16; ++j)
      acc[j] = __builtin_amdgcn_mfma_f32_16x16x32_bf16(afrag, bfr[j], acc[j],
                                                       0, 0, 0);
  }

  // ---- epilogue: rows m0+wid*16+l4*4(+r), cols j*16+l15 ----
  {
    const int m = m0 + wid * 16 + l4 * 4;
    const int bb = m >> 12;
    const int pos = m & 4095;
#pragma unroll
    for (int j = 0; j < 16; ++j) {
      const int o = j * 16 + l15;
      *(f32x4*)(out + (((size_t)bb * OCH + o) << 12) + pos) = acc[j];
    }
  }
}

extern "C" void kernel_launch(void* const* d_in, const int* in_sizes, int n_in,
                              void* d_out, int out_size, void* d_ws,
                              size_t ws_size, hipStream_t stream) {
  const float* x = (const float*)d_in[0];
  const float* w_off = (const float*)d_in[1];
  const float* b_off = (const float*)d_in[2];
  const float* w_dcn = (const float*)d_in[3];
  float* out = (float*)d_out;

  char* ws = (char*)d_ws;
  float* off_buf = (float*)(ws);                            //  2,359,296 B
  unsigned short* Wop = (unsigned short*)(ws + 2359296);    //    147,456 B
  unsigned short* zp = (unsigned short*)(ws + 2506752);     //      1,024 B
  unsigned short* W2 = (unsigned short*)(ws + 2507776);     //  1,179,648 B
  unsigned short* xTbf = (unsigned short*)(ws + 3687424);   // 16,777,216 B
  // total 20,464,640 B

  prep_xpose<<<4352, 256, 0, stream>>>(x, w_dcn, w_off, xTbf, W2, Wop, zp);
  offset_gemm<<<256, 512, 0, stream>>>(xTbf, Wop, zp, b_off, off_buf);
  dcn_fused<<<256, 512, 0, stream>>>(xTbf, off_buf, W2, out);
}

// Round 15
// 114.621 us; speedup vs baseline: 1.2660x; 1.2660x over previous
//
#include <hip/hip_runtime.h>
#include <hip/hip_bf16.h>

// Deformable conv via FUSED implicit GEMM on MFMA.
// B=8, C=256, H=W=64, O=256, K=3.
// R15: dcn_fused = R13/R9 verbatim (proven best, 92us; 7 schedule archetypes
//   all >= it). offset_gemm gets the proven BK 32->64 lever (36 steps,
//   half the barrier/drain overhead, R9's validated A-layout/swizzle).

#define HW 64
#define CCH 256
#define OCH 256
#define BB 8
#define KDIM 2304  // 9 * 256, order kk*256 + c

typedef __attribute__((ext_vector_type(8))) short bf16x8;
typedef __attribute__((ext_vector_type(8))) unsigned short u16x8;
typedef __attribute__((ext_vector_type(4))) float f32x4;
typedef __attribute__((ext_vector_type(2))) float f32x2;
typedef __attribute__((ext_vector_type(4))) unsigned short u16x4;
typedef __attribute__((ext_vector_type(4))) unsigned int u32x4;

static __device__ inline unsigned short f2bf(float f) {
  unsigned u = __builtin_bit_cast(unsigned, f);
  u += 0x7FFFu + ((u >> 16) & 1u);  // RNE
  return (unsigned short)(u >> 16);
}
static __device__ inline float bf2f(unsigned short s) {
  return __builtin_bit_cast(float, (unsigned)s << 16);
}
static __device__ inline unsigned cvt_pk_bf16(float lo, float hi) {
  unsigned r;
  asm("v_cvt_pk_bf16_f32 %0, %1, %2" : "=v"(r) : "v"(lo), "v"(hi));
  return r;
}

#define GLL16(gsrc, ldst)                                                      \
  __builtin_amdgcn_global_load_lds(                                           \
      (const __attribute__((address_space(1))) void*)(gsrc),                  \
      (__attribute__((address_space(3))) void*)(ldst), 16, 0, 0)

static __device__ inline int xcd_swz256(int bid) {
  return (bid & 7) * 32 + (bid >> 3);
}

// ---------------- prep_xpose: merged (validated R13) ----------------
__global__ __launch_bounds__(256) void prep_xpose(
    const float* __restrict__ x, const float* __restrict__ w_dcn,
    const float* __restrict__ w_off, unsigned short* __restrict__ xTbf,
    unsigned short* __restrict__ W2, unsigned short* __restrict__ Wop,
    unsigned short* __restrict__ zp) {
  const int tid = threadIdx.x;
  const int bid = blockIdx.x;
  if (bid < 2048) {
    __shared__ float t[64][65];
    const int ct = bid & 3;
    const int pt = (bid >> 2) & 63;
    const int b = bid >> 8;
#pragma unroll
    for (int i = 0; i < 16; ++i) {
      int cl = i * 4 + (tid >> 6);
      int p = tid & 63;
      t[cl][p] = x[(((b << 8) + ct * 64 + cl) << 12) + pt * 64 + p];
    }
    __syncthreads();
#pragma unroll
    for (int i = 0; i < 4; ++i) {
      int pl = i * 16 + (tid >> 4);
      int c4 = (tid & 15) * 4;
      u16x4 v;
      v[0] = f2bf(t[c4][pl]);
      v[1] = f2bf(t[c4 + 1][pl]);
      v[2] = f2bf(t[c4 + 2][pl]);
      v[3] = f2bf(t[c4 + 3][pl]);
      *(u16x4*)(xTbf + (((size_t)((b << 12) + pt * 64 + pl)) << 8) + ct * 64 +
                c4) = v;
    }
  } else {
    int i = (bid - 2048) * 256 + tid;
    if (i < 9 * 256 * 256) {
      int o = i / KDIM;
      int r = i - o * KDIM;
      int kk = r >> 8, c = r & 255;
      W2[i] = f2bf(w_dcn[((o << 8) + c) * 9 + kk]);
    }
    if (i < 32 * KDIM) {
      int n = i / KDIM;
      int r = i - n * KDIM;
      int kk = r >> 8, c = r & 255;
      Wop[i] = (n < 18) ? f2bf(w_off[((n << 8) + c) * 9 + kk]) : (unsigned short)0;
    }
    if (i < 512) zp[i] = 0;
  }
}

// ---------------- offset_gemm (R15: BK=64, 36 steps) ----------------
// BM=128, BN=32(18), BK=64, grid=256, 512 threads / 8 waves.
// A [128][64] LDS, chunk ^= (row&7) (R9-validated layout); staged by 2
// GLL16/thread with pre-swizzled im2col source. B [32][64], 1 GLL16 for
// tid<256, source pre-swizzled. 4 MFMA/wave/step.
__global__ __launch_bounds__(512) void offset_gemm(
    const unsigned short* __restrict__ xTbf, const unsigned short* __restrict__ Wop,
    const unsigned short* __restrict__ zp, const float* __restrict__ b_off,
    float* __restrict__ off_buf) {
  __shared__ short ldsA[2][128 * 64];  // 32KB
  __shared__ short ldsB[2][32 * 64];   // 8KB
  const int tid = threadIdx.x;
  const int lane = tid & 63;
  const int wid = __builtin_amdgcn_readfirstlane(tid >> 6);
  const int m0 = xcd_swz256(blockIdx.x) * 128;
  const int b = m0 >> 12;
  const unsigned short* xb = xTbf + ((size_t)b << 20);

  // A staging: idx = g*512+tid -> row=idx>>3 (0..127), chunk=idx&7.
  int hA[2], wA2[2], scA[2], dstA[2];
#pragma unroll
  for (int g = 0; g < 2; ++g) {
    const int idx = g * 512 + tid;
    const int r = idx >> 3, c = idx & 7;
    const int pos = (m0 & 4095) + r;
    hA[g] = pos >> 6;
    wA2[g] = pos & 63;
    scA[g] = ((c ^ (r & 7)) << 3);  // pre-swizzled source chunk (shorts)
    dstA[g] = idx * 8;              // lane-linear LDS dst
  }
  // B staging: tid<256 -> row=tid>>3 (0..31), chunk=tid&7, src pre-swizzled.
  const int rBs = tid >> 3;
  const unsigned short* srcB =
      Wop + (size_t)rBs * KDIM + (((tid & 7) ^ (rBs & 7)) << 3);

  const int l15 = lane & 15, l4 = lane >> 4;
  const int rA = wid * 16 + l15;
  int offA[2], offB[2][2];
#pragma unroll
  for (int h = 0; h < 2; ++h) {
    offA[h] = rA * 64 + (((h * 4 + l4) ^ (rA & 7)) << 3);
#pragma unroll
    for (int f = 0; f < 2; ++f) {
      const int rb = f * 16 + l15;
      offB[f][h] = rb * 64 + (((h * 4 + l4) ^ (rb & 7)) << 3);
    }
  }

  const f32x4 z = {0.f, 0.f, 0.f, 0.f};
  f32x4 acc[2];
  acc[0] = z;
  acc[1] = z;

  auto stage = [&](int buf, int t) {
    const int tap = t >> 2;
    const int c0 = (t & 3) * 64;
    const int dy = tap / 3 - 1, dx = tap - (tap / 3) * 3 - 1;
#pragma unroll
    for (int g = 0; g < 2; ++g) {
      const int y = hA[g] + dy, xx = wA2[g] + dx;
      const bool valid = ((unsigned)y < 64u) && ((unsigned)xx < 64u);
      const unsigned short* src =
          valid ? xb + ((((y << 6) + xx) << 8) + c0 + scA[g]) : zp + scA[g];
      GLL16(src, &ldsA[buf][dstA[g]]);
    }
    if (tid < 256) GLL16(srcB + t * 64, &ldsB[buf][tid * 8]);
  };

  stage(0, 0);
  __syncthreads();

  for (int t = 0; t < 36; ++t) {
    const int buf = t & 1;
    if (t < 35) stage(buf ^ 1, t + 1);
#pragma unroll
    for (int h = 0; h < 2; ++h) {
      bf16x8 af = *(const bf16x8*)&ldsA[buf][offA[h]];
      bf16x8 bfr[2];
#pragma unroll
      for (int f = 0; f < 2; ++f) bfr[f] = *(const bf16x8*)&ldsB[buf][offB[f][h]];
#pragma unroll
      for (int j = 0; j < 2; ++j)
        acc[j] = __builtin_amdgcn_mfma_f32_16x16x32_bf16(af, bfr[j], acc[j],
                                                         0, 0, 0);
    }
    __syncthreads();
  }

#pragma unroll
  for (int j = 0; j < 2; ++j) {
    const int col = j * 16 + l15;
    if (col < 18) {
      const float bias = b_off[col];
#pragma unroll
      for (int rr = 0; rr < 4; ++rr) {
        const int m = m0 + wid * 16 + l4 * 4 + rr;
        off_buf[(size_t)m * 18 + col] = acc[j][rr] + bias;
      }
    }
  }
}

// ---------------- dcn_fused (R9/R13 verbatim: bf16, BK=64) ----------------
__global__ __launch_bounds__(512, 2) void dcn_fused(
    const unsigned short* __restrict__ xTbf, const float* __restrict__ off_buf,
    const unsigned short* __restrict__ W2, float* __restrict__ out) {
  __shared__ f32x2 slyx[128][9];   // (ly, lx)
  __shared__ u16x4 spos[128][9];   // corner pos (12b) | validity<<15
  __shared__ short ldsA[2][128 * 64];   // 32KB
  __shared__ short ldsB[2][256 * 64];   // 64KB

  const int tid = threadIdx.x;
  const int lane = tid & 63;
  const int wid = __builtin_amdgcn_readfirstlane(tid >> 6);
  const int m0 = xcd_swz256(blockIdx.x) * 128;
  const int b = m0 >> 12;
  const unsigned short* xb = xTbf + ((size_t)b << 20);

  // ---- phase 0: sampling params for 128 rows x 9 taps ----
  for (int idx = tid; idx < 128 * 9; idx += 512) {
    const int r = idx / 9, k = idx - (idx / 9) * 9;
    const int ky = k / 3, kx = k - ky * 3;
    const int pos = (m0 & 4095) + r;
    const int h = pos >> 6, w = pos & 63;
    const float offy = off_buf[(size_t)(m0 + r) * 18 + 2 * k];
    const float offx = off_buf[(size_t)(m0 + r) * 18 + 2 * k + 1];
    const float sy = offy + (float)(h - 1 + ky);
    const float sx = offx + (float)(w - 1 + kx);
    const float y0f = floorf(sy), x0f = floorf(sx);
    const int y0 = (int)y0f, x0 = (int)x0f;
    const int y1 = y0 + 1, x1 = x0 + 1;
    const unsigned vy0 = ((unsigned)y0 < 64u), vy1 = ((unsigned)y1 < 64u);
    const unsigned vx0 = ((unsigned)x0 < 64u), vx1 = ((unsigned)x1 < 64u);
    const int y0c = min(max(y0, 0), HW - 1), y1c = min(max(y1, 0), HW - 1);
    const int x0c = min(max(x0, 0), HW - 1), x1c = min(max(x1, 0), HW - 1);
    f32x2 lyx;
    lyx[0] = sy - y0f;
    lyx[1] = sx - x0f;
    u16x4 pp;
    pp[0] = (unsigned short)(((y0c << 6) + x0c) | ((vy0 & vx0) << 15));
    pp[1] = (unsigned short)(((y0c << 6) + x1c) | ((vy0 & vx1) << 15));
    pp[2] = (unsigned short)(((y1c << 6) + x0c) | ((vy1 & vx0) << 15));
    pp[3] = (unsigned short)(((y1c << 6) + x1c) | ((vy1 & vx1) << 15));
    slyx[r][k] = lyx;
    spos[r][k] = pp;
  }

  // ---- roles ----
  const int r = tid >> 2, q = tid & 3;  // sampling: row, 16-ch sixteenth
  const int dstA0 = r * 64 + (((2 * q) ^ (r & 7)) << 3);
  const int dstA1 = r * 64 + (((2 * q + 1) ^ (r & 7)) << 3);

  // B staging: 4 GLLs; dst lane-linear (idx*8 shorts), source pre-swizzled.
  const unsigned short* srcBp[4];
  int dstB[4];
#pragma unroll
  for (int g = 0; g < 4; ++g) {
    const int idx = g * 512 + tid;
    const int row = idx >> 3, c = idx & 7;
    srcBp[g] = W2 + (size_t)row * KDIM + ((c ^ (row & 7)) << 3);
    dstB[g] = idx * 8;
  }

  const int l15 = lane & 15, l4 = lane >> 4;
  const int wm = wid & 1, wn = wid >> 1;
  int offA[4][2], offB[4][2];
#pragma unroll
  for (int f = 0; f < 4; ++f) {
    const int rA = wm * 64 + f * 16 + l15;
    const int rB = wn * 64 + f * 16 + l15;
#pragma unroll
    for (int h = 0; h < 2; ++h) {
      offA[f][h] = rA * 64 + (((h * 4 + l4) ^ (rA & 7)) << 3);
      offB[f][h] = rB * 64 + (((h * 4 + l4) ^ (rB & 7)) << 3);
    }
  }

  const f32x4 z = {0.f, 0.f, 0.f, 0.f};
  f32x4 acc[4][4];
#pragma unroll
  for (int i = 0; i < 4; ++i)
#pragma unroll
    for (int j = 0; j < 4; ++j) acc[i][j] = z;

  __syncthreads();  // params visible

  // per-tap params
  f32x4 wv;
  int av[4];
  auto load_params = [&](int tap) {
    const f32x2 lyx = slyx[r][tap];
    const u16x4 pp = spos[r][tap];
    const float ly = lyx[0], lx = lyx[1];
#pragma unroll
    for (int e = 0; e < 4; ++e) av[e] = (int)(pp[e] & 0x0FFFu) << 8;
    wv[0] = (1.f - ly) * (1.f - lx) * (float)(pp[0] >> 15);
    wv[1] = (1.f - ly) * lx * (float)(pp[1] >> 15);
    wv[2] = ly * (1.f - lx) * (float)(pp[2] >> 15);
    wv[3] = ly * lx * (float)(pp[3] >> 15);
  };

  // gather regs: 16 channels = 2 u16x8 per corner
  u16x8 gc0[2], gc1[2], gc2[2], gc3[2];
  f32x4 gw;

  auto issue_gathers = [&](int t) {
    const int cb = ((t & 3) << 6) + q * 16;  // channel base within image row
#pragma unroll
    for (int h = 0; h < 2; ++h) {
      gc0[h] = *(const u16x8*)(xb + av[0] + cb + h * 8);
      gc1[h] = *(const u16x8*)(xb + av[1] + cb + h * 8);
      gc2[h] = *(const u16x8*)(xb + av[2] + cb + h * 8);
      gc3[h] = *(const u16x8*)(xb + av[3] + cb + h * 8);
    }
    gw = wv;
  };

  auto lerp_store = [&](int buf) {
    short* base = ldsA[buf];
#pragma unroll
    for (int h = 0; h < 2; ++h) {
      u32x4 wds;
#pragma unroll
      for (int e = 0; e < 4; ++e) {
        const float f0 = gw[0] * bf2f(gc0[h][2 * e]) + gw[1] * bf2f(gc1[h][2 * e]) +
                         gw[2] * bf2f(gc2[h][2 * e]) + gw[3] * bf2f(gc3[h][2 * e]);
        const float f1 = gw[0] * bf2f(gc0[h][2 * e + 1]) +
                         gw[1] * bf2f(gc1[h][2 * e + 1]) +
                         gw[2] * bf2f(gc2[h][2 * e + 1]) +
                         gw[3] * bf2f(gc3[h][2 * e + 1]);
        wds[e] = cvt_pk_bf16(f0, f1);
      }
      *(u32x4*)&base[h == 0 ? dstA0 : dstA1] = wds;
    }
  };

  // ---- prologue: tile 0 ----
  load_params(0);
  issue_gathers(0);
  lerp_store(0);
#pragma unroll
  for (int g = 0; g < 4; ++g) GLL16(srcBp[g], &ldsB[0][dstB[g]]);
  __syncthreads();

  // ---- main loop: 36 K-steps ----
  for (int t = 0; t < 36; ++t) {
    const int buf = t & 1;
    if (t < 35) {
      const int tn = t + 1;
#pragma unroll
      for (int g = 0; g < 4; ++g) GLL16(srcBp[g] + tn * 64, &ldsB[buf ^ 1][dstB[g]]);
      if ((tn & 3) == 0) load_params(tn >> 2);
      issue_gathers(tn);  // early issue (T14)
    }
#pragma unroll
    for (int h = 0; h < 2; ++h) {
      bf16x8 af[4], bfr[4];
#pragma unroll
      for (int f = 0; f < 4; ++f) {
        af[f] = *(const bf16x8*)&ldsA[buf][offA[f][h]];
        bfr[f] = *(const bf16x8*)&ldsB[buf][offB[f][h]];
      }
#pragma unroll
      for (int i = 0; i < 4; ++i)
#pragma unroll
        for (int j = 0; j < 4; ++j)
          acc[i][j] = __builtin_amdgcn_mfma_f32_16x16x32_bf16(af[i], bfr[j],
                                                              acc[i][j], 0, 0, 0);
    }
    if (t < 35) lerp_store(buf ^ 1);  // late write: gathers covered by MFMAs
    __syncthreads();
  }

  // ---- epilogue ----
#pragma unroll
  for (int i = 0; i < 4; ++i) {
    const int m = m0 + wm * 64 + i * 16 + l4 * 4;
    const int bb = m >> 12;
    const int pos = m & 4095;
#pragma unroll
    for (int j = 0; j < 4; ++j) {
      const int o = wn * 64 + j * 16 + l15;
      *(f32x4*)(out + (((size_t)bb * OCH + o) << 12) + pos) = acc[i][j];
    }
  }
}

extern "C" void kernel_launch(void* const* d_in, const int* in_sizes, int n_in,
                              void* d_out, int out_size, void* d_ws,
                              size_t ws_size, hipStream_t stream) {
  const float* x = (const float*)d_in[0];
  const float* w_off = (const float*)d_in[1];
  const float* b_off = (const float*)d_in[2];
  const float* w_dcn = (const float*)d_in[3];
  float* out = (float*)d_out;

  char* ws = (char*)d_ws;
  float* off_buf = (float*)(ws);                            //  2,359,296 B
  unsigned short* Wop = (unsigned short*)(ws + 2359296);    //    147,456 B
  unsigned short* zp = (unsigned short*)(ws + 2506752);     //      1,024 B
  unsigned short* W2 = (unsigned short*)(ws + 2507776);     //  1,179,648 B
  unsigned short* xTbf = (unsigned short*)(ws + 3687424);   // 16,777,216 B
  // total 20,464,640 B

  prep_xpose<<<4352, 256, 0, stream>>>(x, w_dcn, w_off, xTbf, W2, Wop, zp);
  offset_gemm<<<256, 512, 0, stream>>>(xTbf, Wop, zp, b_off, off_buf);
  dcn_fused<<<256, 512, 0, stream>>>(xTbf, off_buf, W2, out);
}

// Round 16
// 105.632 us; speedup vs baseline: 1.3738x; 1.0851x over previous
//
#include <hip/hip_runtime.h>
#include <hip/hip_bf16.h>

// Deformable conv via FUSED implicit GEMM on MFMA.
// B=8, C=256, H=W=64, O=256, K=3.
// R16: (1) offset GEMM folded into dcn_fused as a per-block prologue
//   (R15-validated body; offsets -> LDS soff, no off_buf round-trip, one
//   fewer dispatch). (2) lerp uses v_pk_fma_f32 on bf16 pairs (1 shift +
//   1 and unpack, half the FMA instrs; same f32 math). Rest = R15 verbatim.

#define HW 64
#define CCH 256
#define OCH 256
#define BB 8
#define KDIM 2304  // 9 * 256, order kk*256 + c

typedef __attribute__((ext_vector_type(8))) short bf16x8;
typedef __attribute__((ext_vector_type(8))) unsigned short u16x8;
typedef __attribute__((ext_vector_type(4))) float f32x4;
typedef __attribute__((ext_vector_type(2))) float f32x2;
typedef __attribute__((ext_vector_type(4))) unsigned short u16x4;
typedef __attribute__((ext_vector_type(4))) unsigned int u32x4;

static __device__ inline unsigned short f2bf(float f) {
  unsigned u = __builtin_bit_cast(unsigned, f);
  u += 0x7FFFu + ((u >> 16) & 1u);  // RNE
  return (unsigned short)(u >> 16);
}
static __device__ inline unsigned cvt_pk_bf16(float lo, float hi) {
  unsigned r;
  asm("v_cvt_pk_bf16_f32 %0, %1, %2" : "=v"(r) : "v"(lo), "v"(hi));
  return r;
}
static __device__ inline f32x2 pk_mul_f32(f32x2 a, f32x2 b) {
  f32x2 d;
  asm("v_pk_mul_f32 %0, %1, %2" : "=v"(d) : "v"(a), "v"(b));
  return d;
}
static __device__ inline f32x2 pk_fma_f32(f32x2 a, f32x2 b, f32x2 c) {
  f32x2 d;
  asm("v_pk_fma_f32 %0, %1, %2, %3" : "=v"(d) : "v"(a), "v"(b), "v"(c));
  return d;
}
// packed 2x bf16 (u32) -> f32x2 {lo<<16, hi&0xFFFF0000} (exact)
static __device__ inline f32x2 unpk_bf16(unsigned p) {
  f32x2 r;
  r[0] = __builtin_bit_cast(float, p << 16);
  r[1] = __builtin_bit_cast(float, p & 0xFFFF0000u);
  return r;
}

#define GLL16(gsrc, ldst)                                                      \
  __builtin_amdgcn_global_load_lds(                                           \
      (const __attribute__((address_space(1))) void*)(gsrc),                  \
      (__attribute__((address_space(3))) void*)(ldst), 16, 0, 0)

static __device__ inline int xcd_swz256(int bid) {
  return (bid & 7) * 32 + (bid >> 3);
}

// ---------------- prep_xpose: merged (validated R13) ----------------
__global__ __launch_bounds__(256) void prep_xpose(
    const float* __restrict__ x, const float* __restrict__ w_dcn,
    const float* __restrict__ w_off, unsigned short* __restrict__ xTbf,
    unsigned short* __restrict__ W2, unsigned short* __restrict__ Wop,
    unsigned short* __restrict__ zp) {
  const int tid = threadIdx.x;
  const int bid = blockIdx.x;
  if (bid < 2048) {
    __shared__ float t[64][65];
    const int ct = bid & 3;
    const int pt = (bid >> 2) & 63;
    const int b = bid >> 8;
#pragma unroll
    for (int i = 0; i < 16; ++i) {
      int cl = i * 4 + (tid >> 6);
      int p = tid & 63;
      t[cl][p] = x[(((b << 8) + ct * 64 + cl) << 12) + pt * 64 + p];
    }
    __syncthreads();
#pragma unroll
    for (int i = 0; i < 4; ++i) {
      int pl = i * 16 + (tid >> 4);
      int c4 = (tid & 15) * 4;
      u16x4 v;
      v[0] = f2bf(t[c4][pl]);
      v[1] = f2bf(t[c4 + 1][pl]);
      v[2] = f2bf(t[c4 + 2][pl]);
      v[3] = f2bf(t[c4 + 3][pl]);
      *(u16x4*)(xTbf + (((size_t)((b << 12) + pt * 64 + pl)) << 8) + ct * 64 +
                c4) = v;
    }
  } else {
    int i = (bid - 2048) * 256 + tid;
    if (i < 9 * 256 * 256) {
      int o = i / KDIM;
      int r = i - o * KDIM;
      int kk = r >> 8, c = r & 255;
      W2[i] = f2bf(w_dcn[((o << 8) + c) * 9 + kk]);
    }
    if (i < 32 * KDIM) {
      int n = i / KDIM;
      int r = i - n * KDIM;
      int kk = r >> 8, c = r & 255;
      Wop[i] = (n < 18) ? f2bf(w_off[((n << 8) + c) * 9 + kk]) : (unsigned short)0;
    }
    if (i < 512) zp[i] = 0;
  }
}

// ---------------- dcn_fused (R16: offset prologue + pk-lerp) ----------------
// Prologue: offset GEMM (BM=128, BN=32(18), BK=64, 36 steps — R15-validated)
//   for this block's rows -> soff[128][18] in LDS.
// Main: R9/R13 structure (BM=128, BN=256, BK=64, 36 steps), pk_fma_f32 lerp.
__global__ __launch_bounds__(512, 2) void dcn_fused(
    const unsigned short* __restrict__ xTbf, const unsigned short* __restrict__ Wop,
    const unsigned short* __restrict__ zp, const float* __restrict__ b_off,
    const unsigned short* __restrict__ W2, float* __restrict__ out) {
  __shared__ float soff[128][18];       // 9.2KB  (prologue output)
  __shared__ f32x2 slyx[128][9];        // 9.2KB
  __shared__ u16x4 spos[128][9];        // 9.2KB
  __shared__ short ldsA[2][128 * 64];   // 32KB
  __shared__ short ldsB[2][256 * 64];   // 64KB

  const int tid = threadIdx.x;
  const int lane = tid & 63;
  const int wid = __builtin_amdgcn_readfirstlane(tid >> 6);
  const int m0 = xcd_swz256(blockIdx.x) * 128;
  const int b = m0 >> 12;
  const unsigned short* xb = xTbf + ((size_t)b << 20);
  const int l15 = lane & 15, l4 = lane >> 4;
  const f32x4 z = {0.f, 0.f, 0.f, 0.f};

  // ======== PROLOGUE: offset GEMM for this block's 128 rows ========
  {
    int phA[2], pwA[2], pscA[2], pdstA[2];
#pragma unroll
    for (int g = 0; g < 2; ++g) {
      const int idx = g * 512 + tid;
      const int pr = idx >> 3, pc = idx & 7;
      const int pos = (m0 & 4095) + pr;
      phA[g] = pos >> 6;
      pwA[g] = pos & 63;
      pscA[g] = ((pc ^ (pr & 7)) << 3);
      pdstA[g] = idx * 8;
    }
    const int rBs = tid >> 3;
    const unsigned short* srcB =
        Wop + (size_t)rBs * KDIM + (((tid & 7) ^ (rBs & 7)) << 3);

    const int rA = wid * 16 + l15;
    int offAp[2], offBp[2][2];
#pragma unroll
    for (int h = 0; h < 2; ++h) {
      offAp[h] = rA * 64 + (((h * 4 + l4) ^ (rA & 7)) << 3);
#pragma unroll
      for (int f = 0; f < 2; ++f) {
        const int rb = f * 16 + l15;
        offBp[f][h] = rb * 64 + (((h * 4 + l4) ^ (rb & 7)) << 3);
      }
    }

    f32x4 pacc[2];
    pacc[0] = z;
    pacc[1] = z;

    auto stage = [&](int buf, int t) {
      const int tap = t >> 2;
      const int c0 = (t & 3) * 64;
      const int dy = tap / 3 - 1, dx = tap - (tap / 3) * 3 - 1;
#pragma unroll
      for (int g = 0; g < 2; ++g) {
        const int y = phA[g] + dy, xx = pwA[g] + dx;
        const bool valid = ((unsigned)y < 64u) && ((unsigned)xx < 64u);
        const unsigned short* src =
            valid ? xb + ((((y << 6) + xx) << 8) + c0 + pscA[g]) : zp + pscA[g];
        GLL16(src, &ldsA[buf][pdstA[g]]);
      }
      if (tid < 256) GLL16(srcB + t * 64, &ldsB[buf][tid * 8]);
    };

    stage(0, 0);
    __syncthreads();

    for (int t = 0; t < 36; ++t) {
      const int buf = t & 1;
      if (t < 35) stage(buf ^ 1, t + 1);
#pragma unroll
      for (int h = 0; h < 2; ++h) {
        bf16x8 af = *(const bf16x8*)&ldsA[buf][offAp[h]];
        bf16x8 bfr[2];
#pragma unroll
        for (int f = 0; f < 2; ++f)
          bfr[f] = *(const bf16x8*)&ldsB[buf][offBp[f][h]];
#pragma unroll
        for (int j = 0; j < 2; ++j)
          pacc[j] = __builtin_amdgcn_mfma_f32_16x16x32_bf16(af, bfr[j],
                                                            pacc[j], 0, 0, 0);
      }
      __syncthreads();
    }

#pragma unroll
    for (int j = 0; j < 2; ++j) {
      const int col = j * 16 + l15;
      if (col < 18) {
        const float bias = b_off[col];
#pragma unroll
        for (int rr = 0; rr < 4; ++rr)
          soff[wid * 16 + l4 * 4 + rr][col] = pacc[j][rr] + bias;
      }
    }
    __syncthreads();
  }

  // ---- phase 0: sampling params for 128 rows x 9 taps (from soff) ----
  for (int idx = tid; idx < 128 * 9; idx += 512) {
    const int r = idx / 9, k = idx - (idx / 9) * 9;
    const int ky = k / 3, kx = k - ky * 3;
    const int pos = (m0 & 4095) + r;
    const int h = pos >> 6, w = pos & 63;
    const float offy = soff[r][2 * k];
    const float offx = soff[r][2 * k + 1];
    const float sy = offy + (float)(h - 1 + ky);
    const float sx = offx + (float)(w - 1 + kx);
    const float y0f = floorf(sy), x0f = floorf(sx);
    const int y0 = (int)y0f, x0 = (int)x0f;
    const int y1 = y0 + 1, x1 = x0 + 1;
    const unsigned vy0 = ((unsigned)y0 < 64u), vy1 = ((unsigned)y1 < 64u);
    const unsigned vx0 = ((unsigned)x0 < 64u), vx1 = ((unsigned)x1 < 64u);
    const int y0c = min(max(y0, 0), HW - 1), y1c = min(max(y1, 0), HW - 1);
    const int x0c = min(max(x0, 0), HW - 1), x1c = min(max(x1, 0), HW - 1);
    f32x2 lyx;
    lyx[0] = sy - y0f;
    lyx[1] = sx - x0f;
    u16x4 pp;
    pp[0] = (unsigned short)(((y0c << 6) + x0c) | ((vy0 & vx0) << 15));
    pp[1] = (unsigned short)(((y0c << 6) + x1c) | ((vy0 & vx1) << 15));
    pp[2] = (unsigned short)(((y1c << 6) + x0c) | ((vy1 & vx0) << 15));
    pp[3] = (unsigned short)(((y1c << 6) + x1c) | ((vy1 & vx1) << 15));
    slyx[r][k] = lyx;
    spos[r][k] = pp;
  }

  // ---- roles ----
  const int r = tid >> 2, q = tid & 3;  // sampling: row, 16-ch sixteenth
  const int dstA0 = r * 64 + (((2 * q) ^ (r & 7)) << 3);
  const int dstA1 = r * 64 + (((2 * q + 1) ^ (r & 7)) << 3);

  // B staging: 4 GLLs; dst lane-linear, source pre-swizzled.
  const unsigned short* srcBp[4];
  int dstB[4];
#pragma unroll
  for (int g = 0; g < 4; ++g) {
    const int idx = g * 512 + tid;
    const int row = idx >> 3, c = idx & 7;
    srcBp[g] = W2 + (size_t)row * KDIM + ((c ^ (row & 7)) << 3);
    dstB[g] = idx * 8;
  }

  const int wm = wid & 1, wn = wid >> 1;
  int offA[4][2], offB[4][2];
#pragma unroll
  for (int f = 0; f < 4; ++f) {
    const int rA = wm * 64 + f * 16 + l15;
    const int rB = wn * 64 + f * 16 + l15;
#pragma unroll
    for (int h = 0; h < 2; ++h) {
      offA[f][h] = rA * 64 + (((h * 4 + l4) ^ (rA & 7)) << 3);
      offB[f][h] = rB * 64 + (((h * 4 + l4) ^ (rB & 7)) << 3);
    }
  }

  f32x4 acc[4][4];
#pragma unroll
  for (int i = 0; i < 4; ++i)
#pragma unroll
    for (int j = 0; j < 4; ++j) acc[i][j] = z;

  __syncthreads();  // params visible

  // per-tap params (weights as broadcast f32x2 pairs for pk math)
  f32x2 wpk[4];
  int av[4];
  auto load_params = [&](int tap) {
    const f32x2 lyx = slyx[r][tap];
    const u16x4 pp = spos[r][tap];
    const float ly = lyx[0], lx = lyx[1];
#pragma unroll
    for (int e = 0; e < 4; ++e) av[e] = (int)(pp[e] & 0x0FFFu) << 8;
    float wf[4];
    wf[0] = (1.f - ly) * (1.f - lx) * (float)(pp[0] >> 15);
    wf[1] = (1.f - ly) * lx * (float)(pp[1] >> 15);
    wf[2] = ly * (1.f - lx) * (float)(pp[2] >> 15);
    wf[3] = ly * lx * (float)(pp[3] >> 15);
#pragma unroll
    for (int e = 0; e < 4; ++e) {
      wpk[e][0] = wf[e];
      wpk[e][1] = wf[e];
    }
  };

  // gather regs: 16 channels = 2 u16x8 per corner
  u16x8 gc0[2], gc1[2], gc2[2], gc3[2];
  f32x2 gwpk[4];

  auto issue_gathers = [&](int t) {
    const int cb = ((t & 3) << 6) + q * 16;
#pragma unroll
    for (int h = 0; h < 2; ++h) {
      gc0[h] = *(const u16x8*)(xb + av[0] + cb + h * 8);
      gc1[h] = *(const u16x8*)(xb + av[1] + cb + h * 8);
      gc2[h] = *(const u16x8*)(xb + av[2] + cb + h * 8);
      gc3[h] = *(const u16x8*)(xb + av[3] + cb + h * 8);
    }
#pragma unroll
    for (int e = 0; e < 4; ++e) gwpk[e] = wpk[e];
  };

  // packed-f32 lerp: per bf16 pair, 8 unpack ops + 1 pk_mul + 3 pk_fma + cvt.
  auto lerp_store = [&](int buf) {
    short* base = ldsA[buf];
#pragma unroll
    for (int h = 0; h < 2; ++h) {
      const u32x4 c0 = __builtin_bit_cast(u32x4, gc0[h]);
      const u32x4 c1 = __builtin_bit_cast(u32x4, gc1[h]);
      const u32x4 c2 = __builtin_bit_cast(u32x4, gc2[h]);
      const u32x4 c3 = __builtin_bit_cast(u32x4, gc3[h]);
      u32x4 wds;
#pragma unroll
      for (int e = 0; e < 4; ++e) {
        f32x2 s = pk_mul_f32(unpk_bf16(c0[e]), gwpk[0]);
        s = pk_fma_f32(unpk_bf16(c1[e]), gwpk[1], s);
        s = pk_fma_f32(unpk_bf16(c2[e]), gwpk[2], s);
        s = pk_fma_f32(unpk_bf16(c3[e]), gwpk[3], s);
        wds[e] = cvt_pk_bf16(s[0], s[1]);
      }
      *(u32x4*)&base[h == 0 ? dstA0 : dstA1] = wds;
    }
  };

  // ---- prologue: tile 0 ----
  load_params(0);
  issue_gathers(0);
  lerp_store(0);
#pragma unroll
  for (int g = 0; g < 4; ++g) GLL16(srcBp[g], &ldsB[0][dstB[g]]);
  __syncthreads();

  // ---- main loop: 36 K-steps ----
  for (int t = 0; t < 36; ++t) {
    const int buf = t & 1;
    if (t < 35) {
      const int tn = t + 1;
#pragma unroll
      for (int g = 0; g < 4; ++g) GLL16(srcBp[g] + tn * 64, &ldsB[buf ^ 1][dstB[g]]);
      if ((tn & 3) == 0) load_params(tn >> 2);
      issue_gathers(tn);  // early issue (T14)
    }
#pragma unroll
    for (int h = 0; h < 2; ++h) {
      bf16x8 af[4], bfr[4];
#pragma unroll
      for (int f = 0; f < 4; ++f) {
        af[f] = *(const bf16x8*)&ldsA[buf][offA[f][h]];
        bfr[f] = *(const bf16x8*)&ldsB[buf][offB[f][h]];
      }
#pragma unroll
      for (int i = 0; i < 4; ++i)
#pragma unroll
        for (int j = 0; j < 4; ++j)
          acc[i][j] = __builtin_amdgcn_mfma_f32_16x16x32_bf16(af[i], bfr[j],
                                                              acc[i][j], 0, 0, 0);
    }
    if (t < 35) lerp_store(buf ^ 1);  // late write: gathers covered by MFMAs
    __syncthreads();
  }

  // ---- epilogue ----
#pragma unroll
  for (int i = 0; i < 4; ++i) {
    const int m = m0 + wm * 64 + i * 16 + l4 * 4;
    const int bb = m >> 12;
    const int pos = m & 4095;
#pragma unroll
    for (int j = 0; j < 4; ++j) {
      const int o = wn * 64 + j * 16 + l15;
      *(f32x4*)(out + (((size_t)bb * OCH + o) << 12) + pos) = acc[i][j];
    }
  }
}

extern "C" void kernel_launch(void* const* d_in, const int* in_sizes, int n_in,
                              void* d_out, int out_size, void* d_ws,
                              size_t ws_size, hipStream_t stream) {
  const float* x = (const float*)d_in[0];
  const float* w_off = (const float*)d_in[1];
  const float* b_off = (const float*)d_in[2];
  const float* w_dcn = (const float*)d_in[3];
  float* out = (float*)d_out;

  char* ws = (char*)d_ws;
  unsigned short* Wop = (unsigned short*)(ws + 2359296);    //    147,456 B
  unsigned short* zp = (unsigned short*)(ws + 2506752);     //      1,024 B
  unsigned short* W2 = (unsigned short*)(ws + 2507776);     //  1,179,648 B
  unsigned short* xTbf = (unsigned short*)(ws + 3687424);   // 16,777,216 B
  // total 20,464,640 B (off_buf slot now unused)

  prep_xpose<<<4352, 256, 0, stream>>>(x, w_dcn, w_off, xTbf, W2, Wop, zp);
  dcn_fused<<<256, 512, 0, stream>>>(xTbf, Wop, zp, b_off, W2, out);
}

// Round 17
// 102.777 us; speedup vs baseline: 1.4119x; 1.0278x over previous
//
#include <hip/hip_runtime.h>
#include <hip/hip_bf16.h>

// Deformable conv via FUSED implicit GEMM on MFMA.
// B=8, C=256, H=W=64, O=256, K=3.
// R17: offset prologue widened to BK=128 (18 steps, half the barrier drains),
//   LDS unioned with the main loop's A/B region (sequential liveness).
//   Main loop + pk-lerp = R16 verbatim (validated, 105.6us total).

#define HW 64
#define CCH 256
#define OCH 256
#define BB 8
#define KDIM 2304  // 9 * 256, order kk*256 + c

typedef __attribute__((ext_vector_type(8))) short bf16x8;
typedef __attribute__((ext_vector_type(8))) unsigned short u16x8;
typedef __attribute__((ext_vector_type(4))) float f32x4;
typedef __attribute__((ext_vector_type(2))) float f32x2;
typedef __attribute__((ext_vector_type(4))) unsigned short u16x4;
typedef __attribute__((ext_vector_type(4))) unsigned int u32x4;

static __device__ inline unsigned short f2bf(float f) {
  unsigned u = __builtin_bit_cast(unsigned, f);
  u += 0x7FFFu + ((u >> 16) & 1u);  // RNE
  return (unsigned short)(u >> 16);
}
static __device__ inline unsigned cvt_pk_bf16(float lo, float hi) {
  unsigned r;
  asm("v_cvt_pk_bf16_f32 %0, %1, %2" : "=v"(r) : "v"(lo), "v"(hi));
  return r;
}
static __device__ inline f32x2 pk_mul_f32(f32x2 a, f32x2 b) {
  f32x2 d;
  asm("v_pk_mul_f32 %0, %1, %2" : "=v"(d) : "v"(a), "v"(b));
  return d;
}
static __device__ inline f32x2 pk_fma_f32(f32x2 a, f32x2 b, f32x2 c) {
  f32x2 d;
  asm("v_pk_fma_f32 %0, %1, %2, %3" : "=v"(d) : "v"(a), "v"(b), "v"(c));
  return d;
}
// packed 2x bf16 (u32) -> f32x2 {lo<<16, hi&0xFFFF0000} (exact)
static __device__ inline f32x2 unpk_bf16(unsigned p) {
  f32x2 r;
  r[0] = __builtin_bit_cast(float, p << 16);
  r[1] = __builtin_bit_cast(float, p & 0xFFFF0000u);
  return r;
}

#define GLL16(gsrc, ldst)                                                      \
  __builtin_amdgcn_global_load_lds(                                           \
      (const __attribute__((address_space(1))) void*)(gsrc),                  \
      (__attribute__((address_space(3))) void*)(ldst), 16, 0, 0)

static __device__ inline int xcd_swz256(int bid) {
  return (bid & 7) * 32 + (bid >> 3);
}

// ---------------- prep_xpose: merged (validated R13) ----------------
__global__ __launch_bounds__(256) void prep_xpose(
    const float* __restrict__ x, const float* __restrict__ w_dcn,
    const float* __restrict__ w_off, unsigned short* __restrict__ xTbf,
    unsigned short* __restrict__ W2, unsigned short* __restrict__ Wop,
    unsigned short* __restrict__ zp) {
  const int tid = threadIdx.x;
  const int bid = blockIdx.x;
  if (bid < 2048) {
    __shared__ float t[64][65];
    const int ct = bid & 3;
    const int pt = (bid >> 2) & 63;
    const int b = bid >> 8;
#pragma unroll
    for (int i = 0; i < 16; ++i) {
      int cl = i * 4 + (tid >> 6);
      int p = tid & 63;
      t[cl][p] = x[(((b << 8) + ct * 64 + cl) << 12) + pt * 64 + p];
    }
    __syncthreads();
#pragma unroll
    for (int i = 0; i < 4; ++i) {
      int pl = i * 16 + (tid >> 4);
      int c4 = (tid & 15) * 4;
      u16x4 v;
      v[0] = f2bf(t[c4][pl]);
      v[1] = f2bf(t[c4 + 1][pl]);
      v[2] = f2bf(t[c4 + 2][pl]);
      v[3] = f2bf(t[c4 + 3][pl]);
      *(u16x4*)(xTbf + (((size_t)((b << 12) + pt * 64 + pl)) << 8) + ct * 64 +
                c4) = v;
    }
  } else {
    int i = (bid - 2048) * 256 + tid;
    if (i < 9 * 256 * 256) {
      int o = i / KDIM;
      int r = i - o * KDIM;
      int kk = r >> 8, c = r & 255;
      W2[i] = f2bf(w_dcn[((o << 8) + c) * 9 + kk]);
    }
    if (i < 32 * KDIM) {
      int n = i / KDIM;
      int r = i - n * KDIM;
      int kk = r >> 8, c = r & 255;
      Wop[i] = (n < 18) ? f2bf(w_off[((n << 8) + c) * 9 + kk]) : (unsigned short)0;
    }
    if (i < 512) zp[i] = 0;
  }
}

// ---------------- dcn_fused (R17: BK=128 offset prologue, unioned LDS) ------
// LDS union ldsU (96KB = 49152 shorts):
//   prologue: A [2][128*128] @0 (64KB) ; B [2][32*128] @32768 (16KB)
//   main:     A [2][128*64]  @0 (32KB) ; B [2][256*64] @16384 (64KB)
__global__ __launch_bounds__(512, 2) void dcn_fused(
    const unsigned short* __restrict__ xTbf, const unsigned short* __restrict__ Wop,
    const unsigned short* __restrict__ zp, const float* __restrict__ b_off,
    const unsigned short* __restrict__ W2, float* __restrict__ out) {
  __shared__ float soff[128][18];       // 9.2KB  (prologue output)
  __shared__ f32x2 slyx[128][9];        // 9.2KB
  __shared__ u16x4 spos[128][9];        // 9.2KB
  __shared__ short ldsU[49152];         // 96KB union (see header)

  const int tid = threadIdx.x;
  const int lane = tid & 63;
  const int wid = __builtin_amdgcn_readfirstlane(tid >> 6);
  const int m0 = xcd_swz256(blockIdx.x) * 128;
  const int b = m0 >> 12;
  const unsigned short* xb = xTbf + ((size_t)b << 20);
  const int l15 = lane & 15, l4 = lane >> 4;
  const f32x4 z = {0.f, 0.f, 0.f, 0.f};

  // ======== PROLOGUE: offset GEMM, BK=128, 18 steps ========
  {
    // A staging: 4 GLL16/thread. idx=g*512+tid -> row=idx>>4, chunk=idx&15.
    int phA[4], pwA[4], pscA[4], pdstA[4];
#pragma unroll
    for (int g = 0; g < 4; ++g) {
      const int idx = g * 512 + tid;
      const int pr = idx >> 4, pc = idx & 15;
      const int pos = (m0 & 4095) + pr;
      phA[g] = pos >> 6;
      pwA[g] = pos & 63;
      pscA[g] = ((pc ^ (pr & 7)) << 3);  // pre-swizzled source chunk (shorts)
      pdstA[g] = idx * 8;                // lane-linear LDS dst (shorts)
    }
    // B staging: 1 GLL16/thread. row=tid>>4 (0..31), chunk=tid&15.
    const int rBs = tid >> 4;
    const unsigned short* srcB =
        Wop + (size_t)rBs * KDIM + (((tid & 15) ^ (rBs & 7)) << 3);
    const int pdstB = tid * 8;

    const int rA = wid * 16 + l15;
    int offAp[4], offBp[2][4];
#pragma unroll
    for (int h = 0; h < 4; ++h) {
      offAp[h] = rA * 128 + (((h * 4 + l4) ^ (rA & 7)) << 3);
#pragma unroll
      for (int f = 0; f < 2; ++f) {
        const int rb = f * 16 + l15;
        offBp[f][h] = rb * 128 + (((h * 4 + l4) ^ (rb & 7)) << 3);
      }
    }

    f32x4 pacc[2];
    pacc[0] = z;
    pacc[1] = z;

    auto stage = [&](int buf, int t) {
      const int tap = t >> 1;
      const int c0 = (t & 1) * 128;
      const int dy = tap / 3 - 1, dx = tap - (tap / 3) * 3 - 1;
#pragma unroll
      for (int g = 0; g < 4; ++g) {
        const int y = phA[g] + dy, xx = pwA[g] + dx;
        const bool valid = ((unsigned)y < 64u) && ((unsigned)xx < 64u);
        const unsigned short* src =
            valid ? xb + ((((y << 6) + xx) << 8) + c0 + pscA[g]) : zp + pscA[g];
        GLL16(src, &ldsU[buf * 16384 + pdstA[g]]);
      }
      GLL16(srcB + t * 128, &ldsU[32768 + buf * 4096 + pdstB]);
    };

    stage(0, 0);
    __syncthreads();

    for (int t = 0; t < 18; ++t) {
      const int buf = t & 1;
      if (t < 17) stage(buf ^ 1, t + 1);
#pragma unroll
      for (int h = 0; h < 4; ++h) {
        bf16x8 af = *(const bf16x8*)&ldsU[buf * 16384 + offAp[h]];
        bf16x8 bfr[2];
#pragma unroll
        for (int f = 0; f < 2; ++f)
          bfr[f] = *(const bf16x8*)&ldsU[32768 + buf * 4096 + offBp[f][h]];
#pragma unroll
        for (int j = 0; j < 2; ++j)
          pacc[j] = __builtin_amdgcn_mfma_f32_16x16x32_bf16(af, bfr[j],
                                                            pacc[j], 0, 0, 0);
      }
      __syncthreads();
    }

#pragma unroll
    for (int j = 0; j < 2; ++j) {
      const int col = j * 16 + l15;
      if (col < 18) {
        const float bias = b_off[col];
#pragma unroll
        for (int rr = 0; rr < 4; ++rr)
          soff[wid * 16 + l4 * 4 + rr][col] = pacc[j][rr] + bias;
      }
    }
    __syncthreads();
  }

  // ---- phase 0: sampling params for 128 rows x 9 taps (from soff) ----
  for (int idx = tid; idx < 128 * 9; idx += 512) {
    const int r = idx / 9, k = idx - (idx / 9) * 9;
    const int ky = k / 3, kx = k - ky * 3;
    const int pos = (m0 & 4095) + r;
    const int h = pos >> 6, w = pos & 63;
    const float offy = soff[r][2 * k];
    const float offx = soff[r][2 * k + 1];
    const float sy = offy + (float)(h - 1 + ky);
    const float sx = offx + (float)(w - 1 + kx);
    const float y0f = floorf(sy), x0f = floorf(sx);
    const int y0 = (int)y0f, x0 = (int)x0f;
    const int y1 = y0 + 1, x1 = x0 + 1;
    const unsigned vy0 = ((unsigned)y0 < 64u), vy1 = ((unsigned)y1 < 64u);
    const unsigned vx0 = ((unsigned)x0 < 64u), vx1 = ((unsigned)x1 < 64u);
    const int y0c = min(max(y0, 0), HW - 1), y1c = min(max(y1, 0), HW - 1);
    const int x0c = min(max(x0, 0), HW - 1), x1c = min(max(x1, 0), HW - 1);
    f32x2 lyx;
    lyx[0] = sy - y0f;
    lyx[1] = sx - x0f;
    u16x4 pp;
    pp[0] = (unsigned short)(((y0c << 6) + x0c) | ((vy0 & vx0) << 15));
    pp[1] = (unsigned short)(((y0c << 6) + x1c) | ((vy0 & vx1) << 15));
    pp[2] = (unsigned short)(((y1c << 6) + x0c) | ((vy1 & vx0) << 15));
    pp[3] = (unsigned short)(((y1c << 6) + x1c) | ((vy1 & vx1) << 15));
    slyx[r][k] = lyx;
    spos[r][k] = pp;
  }

  // ---- roles (main) ----
  const int r = tid >> 2, q = tid & 3;  // sampling: row, 16-ch sixteenth
  const int dstA0 = r * 64 + (((2 * q) ^ (r & 7)) << 3);
  const int dstA1 = r * 64 + (((2 * q + 1) ^ (r & 7)) << 3);

  // B staging: 4 GLLs; dst lane-linear, source pre-swizzled.
  const unsigned short* srcBp[4];
  int dstB[4];
#pragma unroll
  for (int g = 0; g < 4; ++g) {
    const int idx = g * 512 + tid;
    const int row = idx >> 3, c = idx & 7;
    srcBp[g] = W2 + (size_t)row * KDIM + ((c ^ (row & 7)) << 3);
    dstB[g] = idx * 8;
  }

  const int wm = wid & 1, wn = wid >> 1;
  int offA[4][2], offB[4][2];
#pragma unroll
  for (int f = 0; f < 4; ++f) {
    const int rA = wm * 64 + f * 16 + l15;
    const int rB = wn * 64 + f * 16 + l15;
#pragma unroll
    for (int h = 0; h < 2; ++h) {
      offA[f][h] = rA * 64 + (((h * 4 + l4) ^ (rA & 7)) << 3);
      offB[f][h] = rB * 64 + (((h * 4 + l4) ^ (rB & 7)) << 3);
    }
  }

  f32x4 acc[4][4];
#pragma unroll
  for (int i = 0; i < 4; ++i)
#pragma unroll
    for (int j = 0; j < 4; ++j) acc[i][j] = z;

  __syncthreads();  // params visible

  // per-tap params (weights as broadcast f32x2 pairs for pk math)
  f32x2 wpk[4];
  int av[4];
  auto load_params = [&](int tap) {
    const f32x2 lyx = slyx[r][tap];
    const u16x4 pp = spos[r][tap];
    const float ly = lyx[0], lx = lyx[1];
#pragma unroll
    for (int e = 0; e < 4; ++e) av[e] = (int)(pp[e] & 0x0FFFu) << 8;
    float wf[4];
    wf[0] = (1.f - ly) * (1.f - lx) * (float)(pp[0] >> 15);
    wf[1] = (1.f - ly) * lx * (float)(pp[1] >> 15);
    wf[2] = ly * (1.f - lx) * (float)(pp[2] >> 15);
    wf[3] = ly * lx * (float)(pp[3] >> 15);
#pragma unroll
    for (int e = 0; e < 4; ++e) {
      wpk[e][0] = wf[e];
      wpk[e][1] = wf[e];
    }
  };

  // gather regs: 16 channels = 2 u16x8 per corner
  u16x8 gc0[2], gc1[2], gc2[2], gc3[2];
  f32x2 gwpk[4];

  auto issue_gathers = [&](int t) {
    const int cb = ((t & 3) << 6) + q * 16;
#pragma unroll
    for (int h = 0; h < 2; ++h) {
      gc0[h] = *(const u16x8*)(xb + av[0] + cb + h * 8);
      gc1[h] = *(const u16x8*)(xb + av[1] + cb + h * 8);
      gc2[h] = *(const u16x8*)(xb + av[2] + cb + h * 8);
      gc3[h] = *(const u16x8*)(xb + av[3] + cb + h * 8);
    }
#pragma unroll
    for (int e = 0; e < 4; ++e) gwpk[e] = wpk[e];
  };

  // packed-f32 lerp (R16-validated)
  auto lerp_store = [&](int buf) {
    short* base = &ldsU[buf * 8192];
#pragma unroll
    for (int h = 0; h < 2; ++h) {
      const u32x4 c0 = __builtin_bit_cast(u32x4, gc0[h]);
      const u32x4 c1 = __builtin_bit_cast(u32x4, gc1[h]);
      const u32x4 c2 = __builtin_bit_cast(u32x4, gc2[h]);
      const u32x4 c3 = __builtin_bit_cast(u32x4, gc3[h]);
      u32x4 wds;
#pragma unroll
      for (int e = 0; e < 4; ++e) {
        f32x2 s = pk_mul_f32(unpk_bf16(c0[e]), gwpk[0]);
        s = pk_fma_f32(unpk_bf16(c1[e]), gwpk[1], s);
        s = pk_fma_f32(unpk_bf16(c2[e]), gwpk[2], s);
        s = pk_fma_f32(unpk_bf16(c3[e]), gwpk[3], s);
        wds[e] = cvt_pk_bf16(s[0], s[1]);
      }
      *(u32x4*)&base[h == 0 ? dstA0 : dstA1] = wds;
    }
  };

  // ---- prologue: tile 0 ----
  load_params(0);
  issue_gathers(0);
  lerp_store(0);
#pragma unroll
  for (int g = 0; g < 4; ++g) GLL16(srcBp[g], &ldsU[16384 + dstB[g]]);
  __syncthreads();

  // ---- main loop: 36 K-steps ----
  for (int t = 0; t < 36; ++t) {
    const int buf = t & 1;
    if (t < 35) {
      const int tn = t + 1;
#pragma unroll
      for (int g = 0; g < 4; ++g)
        GLL16(srcBp[g] + tn * 64, &ldsU[16384 + (buf ^ 1) * 16384 + dstB[g]]);
      if ((tn & 3) == 0) load_params(tn >> 2);
      issue_gathers(tn);  // early issue (T14)
    }
#pragma unroll
    for (int h = 0; h < 2; ++h) {
      bf16x8 af[4], bfr[4];
#pragma unroll
      for (int f = 0; f < 4; ++f) {
        af[f] = *(const bf16x8*)&ldsU[buf * 8192 + offA[f][h]];
        bfr[f] = *(const bf16x8*)&ldsU[16384 + buf * 16384 + offB[f][h]];
      }
#pragma unroll
      for (int i = 0; i < 4; ++i)
#pragma unroll
        for (int j = 0; j < 4; ++j)
          acc[i][j] = __builtin_amdgcn_mfma_f32_16x16x32_bf16(af[i], bfr[j],
                                                              acc[i][j], 0, 0, 0);
    }
    if (t < 35) lerp_store(buf ^ 1);  // late write: gathers covered by MFMAs
    __syncthreads();
  }

  // ---- epilogue ----
#pragma unroll
  for (int i = 0; i < 4; ++i) {
    const int m = m0 + wm * 64 + i * 16 + l4 * 4;
    const int bb = m >> 12;
    const int pos = m & 4095;
#pragma unroll
    for (int j = 0; j < 4; ++j) {
      const int o = wn * 64 + j * 16 + l15;
      *(f32x4*)(out + (((size_t)bb * OCH + o) << 12) + pos) = acc[i][j];
    }
  }
}

extern "C" void kernel_launch(void* const* d_in, const int* in_sizes, int n_in,
                              void* d_out, int out_size, void* d_ws,
                              size_t ws_size, hipStream_t stream) {
  const float* x = (const float*)d_in[0];
  const float* w_off = (const float*)d_in[1];
  const float* b_off = (const float*)d_in[2];
  const float* w_dcn = (const float*)d_in[3];
  float* out = (float*)d_out;

  char* ws = (char*)d_ws;
  unsigned short* Wop = (unsigned short*)(ws + 2359296);    //    147,456 B
  unsigned short* zp = (unsigned short*)(ws + 2506752);     //      1,024 B
  unsigned short* W2 = (unsigned short*)(ws + 2507776);     //  1,179,648 B
  unsigned short* xTbf = (unsigned short*)(ws + 3687424);   // 16,777,216 B
  // total 20,464,640 B

  prep_xpose<<<4352, 256, 0, stream>>>(x, w_dcn, w_off, xTbf, W2, Wop, zp);
  dcn_fused<<<256, 512, 0, stream>>>(xTbf, Wop, zp, b_off, W2, out);
}